// Round 5
// baseline (571.114 us; speedup 1.0000x reference)
//
#include <hip/hip_runtime.h>
#include <stdint.h>

#define NTOK 65536          // B*T
#define DE 384
#define QSTR 1280           // padded qkv row stride (1152 -> 1280)

typedef __bf16 bf16x8 __attribute__((ext_vector_type(8)));
typedef float  f32x4 __attribute__((ext_vector_type(4)));
typedef unsigned short u16x8 __attribute__((ext_vector_type(8)));

__device__ __forceinline__ unsigned short f2bf(float f) {
  union { float fl; unsigned u; } a; a.fl = f;
  unsigned r = a.u + 0x7fffu + ((a.u >> 16) & 1u);
  return (unsigned short)(r >> 16);
}

__device__ __forceinline__ void gll16(const void* g, void* l) {
  __builtin_amdgcn_global_load_lds((const __attribute__((address_space(1))) void*)g,
                                   (__attribute__((address_space(3))) void*)l, 16, 0, 0);
}

__device__ __forceinline__ bf16x8 ds128(unsigned addr) {
  bf16x8 r;
  asm volatile("ds_read_b128 %0, %1" : "=v"(r) : "v"(addr));
  return r;
}

template<int N> __device__ __forceinline__ void wait_vmcnt() {
  if constexpr (N == 0) asm volatile("s_waitcnt vmcnt(0)" ::: "memory");
  else if constexpr (N == 3) asm volatile("s_waitcnt vmcnt(3)" ::: "memory");
  else if constexpr (N == 4) asm volatile("s_waitcnt vmcnt(4)" ::: "memory");
  else if constexpr (N == 5) asm volatile("s_waitcnt vmcnt(5)" ::: "memory");
  else if constexpr (N == 6) asm volatile("s_waitcnt vmcnt(6)" ::: "memory");
  else asm volatile("s_waitcnt vmcnt(8)" ::: "memory");
}

// ---------------- weight packing ----------------
__global__ void pack_t(unsigned short* __restrict__ dst, const float* __restrict__ src,
                       int R, int C) {
  int t = blockIdx.x * 256 + threadIdx.x;
  if (t >= R * C) return;
  int r = t / C, c = t - r * C;
  dst[(size_t)c * R + r] = f2bf(src[t]);
}

// Wqkv_t padded [1280][384]: n = which*384 + h*64 + e  (rows >=1152 are zero)
__global__ void qkv_pack(const float* __restrict__ wq, const float* __restrict__ wk,
                         const float* __restrict__ wv, unsigned short* __restrict__ dst) {
  int t = blockIdx.x * 256 + threadIdx.x;
  if (t >= QSTR * 384) return;
  int n = t / 384, k = t - n * 384;
  unsigned short v = 0;
  if (n < 1152) {
    int which = n / 384, r = n - which * 384;
    const float* src = which == 0 ? wq : (which == 1 ? wk : wv);
    int h = r >> 6, e = r & 63;
    v = f2bf(src[h * 24576 + k * 64 + e]);
  }
  dst[t] = v;
}

// ---------------- layernorm (f32 in -> bf16 out), wave per row ----------------
__global__ __launch_bounds__(256) void ln_kernel(const float* __restrict__ x,
                                                 const float* __restrict__ g,
                                                 const float* __restrict__ be,
                                                 unsigned short* __restrict__ out) {
  int wave = threadIdx.x >> 6, lane = threadIdx.x & 63;
  size_t row = (size_t)blockIdx.x * 4 + wave;
  const float* xr = x + row * DE;
  int c0 = lane * 2;
  float2 v0 = *(const float2*)(xr + c0);
  float2 v1 = *(const float2*)(xr + 128 + c0);
  float2 v2 = *(const float2*)(xr + 256 + c0);
  float s  = v0.x + v0.y + v1.x + v1.y + v2.x + v2.y;
  float ss = v0.x*v0.x + v0.y*v0.y + v1.x*v1.x + v1.y*v1.y + v2.x*v2.x + v2.y*v2.y;
#pragma unroll
  for (int m = 1; m < 64; m <<= 1) { s += __shfl_xor(s, m); ss += __shfl_xor(ss, m); }
  float mu = s * (1.0f / 384.0f);
  float rstd = rsqrtf(ss * (1.0f / 384.0f) - mu * mu + 1e-5f);
  unsigned short* orow = out + row * DE;
  {
    float a0 = (v0.x - mu) * rstd * g[c0] + be[c0];
    float a1 = (v0.y - mu) * rstd * g[c0 + 1] + be[c0 + 1];
    *(unsigned*)(orow + c0) = (unsigned)f2bf(a0) | ((unsigned)f2bf(a1) << 16);
  }
  {
    int c = c0 + 128;
    float a0 = (v1.x - mu) * rstd * g[c] + be[c];
    float a1 = (v1.y - mu) * rstd * g[c + 1] + be[c + 1];
    *(unsigned*)(orow + c) = (unsigned)f2bf(a0) | ((unsigned)f2bf(a1) << 16);
  }
  {
    int c = c0 + 256;
    float a0 = (v2.x - mu) * rstd * g[c] + be[c];
    float a1 = (v2.y - mu) * rstd * g[c + 1] + be[c + 1];
    *(unsigned*)(orow + c) = (unsigned)f2bf(a0) | ((unsigned)f2bf(a1) << 16);
  }
}

// ---------------- GEMM core: C[M,N] = A[M,K] @ Bt[N,K]^T ----------------
// BK=32, 4 LDS buffers, prefetch depth 2 tiles, ONE vmcnt(LT)+barrier per tile.
// Pair-packed XOR swizzle: matrix rows 2p,2p+1 share a 128B super-row;
// slot' = (s | (m&1)<<2) ^ (p&7)  -> 2-way (free) bank pattern on frag reads.
// EPI 0: bf16 natural; EPI 1/3: f32 acc+bias+resid; EPI 2: bf16 relu(acc+bias)
template<int EPI, int BM, int BN, int WM, int WN>
__device__ __forceinline__
void gemm_core(const unsigned short* __restrict__ A, const unsigned short* __restrict__ Bt,
               int M, int N, int K, int ntx,
               const float* __restrict__ bias, const float* __restrict__ resid,
               float* __restrict__ outf, unsigned short* __restrict__ outb) {
  constexpr int MWT = BM / WM, NWT = BN / WN;       // per-wave tile
  constexpr int MF = MWT / 16, NF = NWT / 16;
  constexpr int MHF = MF / 2;
  constexpr int LA = (BM * 64) / 8192;              // 8KB staging rounds for A tile
  constexpr int LB = (BN * 64) / 8192;
  constexpr int LT = LA + LB;                        // loads per tile per thread
  __shared__ __align__(16) unsigned short As[4][BM * 32];
  __shared__ __align__(16) unsigned short Bs[4][BN * 32];
  const int tid = threadIdx.x;
  const int wave = tid >> 6, lane = tid & 63;

  const int nwg = gridDim.x;
  const int cpx = nwg >> 3;
  const int wg = (blockIdx.x & 7) * cpx + (blockIdx.x >> 3);
  const int bx = wg % ntx, by = wg / ntx;
  const int mBase = by * BM, nBase = bx * BN;
  const int wm = (wave / WN) * MWT, wn = (wave % WN) * NWT;
  const int fr = lane & 15, fg = lane >> 4;          // fg in 0..3 (16B slot)

  const unsigned asb = (unsigned)(uintptr_t)&As[0][0];
  const unsigned bsb = (unsigned)(uintptr_t)&Bs[0][0];

  f32x4 acc[MF][NF];
  const f32x4 z = {0.f, 0.f, 0.f, 0.f};
#pragma unroll
  for (int i = 0; i < MF; ++i)
#pragma unroll
    for (int j = 0; j < NF; ++j) acc[i][j] = z;

  // stage one 8KB round (idx<LA: A round idx, else B round idx-LA); linear LDS dest,
  // inverse-swizzled global source.
  auto stage_one = [&](int buf, int kt, int idx) {
    if (idx < LA) {
      int Lb = idx * 8192 + wave * 1024;
      int L = Lb + lane * 16;
      int p = L >> 7;
      int sl = ((L >> 4) & 7) ^ (p & 7);
      int m = (p << 1) | (sl >> 2);
      int col = (sl & 3) << 3;
      gll16(A + (size_t)(mBase + m) * K + kt + col, (unsigned short*)As[buf] + (Lb >> 1));
    } else {
      int Lb = (idx - LA) * 8192 + wave * 1024;
      int L = Lb + lane * 16;
      int p = L >> 7;
      int sl = ((L >> 4) & 7) ^ (p & 7);
      int m = (p << 1) | (sl >> 2);
      int col = (sl & 3) << 3;
      gll16(Bt + (size_t)(nBase + m) * K + kt + col, (unsigned short*)Bs[buf] + (Lb >> 1));
    }
  };

  // frag read address for matrix row `row`, 16B slot fg
  auto fraddr = [&](unsigned base, int row) -> unsigned {
    return base + ((unsigned)(row >> 1) << 7) +
           ((unsigned)((fg | ((row & 1) << 2)) ^ ((row >> 1) & 7)) << 4);
  };

  const int NK = K >> 5;
  // prologue: stage tiles 0 and 1
#pragma unroll
  for (int i = 0; i < LT; ++i) stage_one(0, 0, i);
#pragma unroll
  for (int i = 0; i < LT; ++i) stage_one(1, 32, i);

  for (int t = 0; t < NK; ++t) {
    const int cb = t & 3;
    if (t + 1 < NK) wait_vmcnt<LT>();
    else            wait_vmcnt<0>();
    __builtin_amdgcn_s_barrier();

    const unsigned ab = asb + (unsigned)cb * (BM * 64);
    const unsigned bb = bsb + (unsigned)cb * (BN * 64);
    const bool pf = (t + 2) < NK;
    const int pbuf = (t + 2) & 3;
    const int pkt = (t + 2) << 5;

    bf16x8 bfr[NF];
    bf16x8 af[MHF];
    // ---- phase 0: B all + A half0; prefetch loads 0..1 ----
#pragma unroll
    for (int nb = 0; nb < NF; ++nb) bfr[nb] = ds128(fraddr(bb, wn + nb * 16 + fr));
#pragma unroll
    for (int mb = 0; mb < MHF; ++mb) af[mb] = ds128(fraddr(ab, wm + mb * 16 + fr));
    if (pf) {
      stage_one(pbuf, pkt, 0);
      if (LT > 1) stage_one(pbuf, pkt, 1);
    }
    asm volatile("s_waitcnt lgkmcnt(0)" ::: "memory");
    __builtin_amdgcn_sched_barrier(0);
    __builtin_amdgcn_s_setprio(1);
#pragma unroll
    for (int mb = 0; mb < MHF; ++mb)
#pragma unroll
      for (int nb = 0; nb < NF; ++nb)
        acc[mb][nb] = __builtin_amdgcn_mfma_f32_16x16x32_bf16(af[mb], bfr[nb], acc[mb][nb], 0, 0, 0);
    __builtin_amdgcn_s_setprio(0);
    // ---- phase 1: A half1; prefetch loads 2..LT-1 ----
#pragma unroll
    for (int mb = 0; mb < MHF; ++mb) af[mb] = ds128(fraddr(ab, wm + (MHF + mb) * 16 + fr));
    if (pf) {
#pragma unroll
      for (int i = 2; i < LT; ++i) stage_one(pbuf, pkt, i);
    }
    asm volatile("s_waitcnt lgkmcnt(0)" ::: "memory");
    __builtin_amdgcn_sched_barrier(0);
    __builtin_amdgcn_s_setprio(1);
#pragma unroll
    for (int mb = 0; mb < MHF; ++mb)
#pragma unroll
      for (int nb = 0; nb < NF; ++nb)
        acc[MHF + mb][nb] =
            __builtin_amdgcn_mfma_f32_16x16x32_bf16(af[mb], bfr[nb], acc[MHF + mb][nb], 0, 0, 0);
    __builtin_amdgcn_s_setprio(0);
  }

#pragma unroll
  for (int mb = 0; mb < MF; ++mb) {
#pragma unroll
    for (int nb = 0; nb < NF; ++nb) {
      const int gn = nBase + wn + nb * 16 + fr;
#pragma unroll
      for (int i = 0; i < 4; ++i) {
        const int gm = mBase + wm + mb * 16 + (fg << 2) + i;
        float val = acc[mb][nb][i];
        if (EPI == 0) {
          outb[(size_t)gm * N + gn] = f2bf(val);
        } else if (EPI == 1) {
          size_t idx = (size_t)gm * N + gn;
          outf[idx] = val + bias[gn] + resid[idx];
        } else if (EPI == 2) {
          float r = val + bias[gn];
          outb[(size_t)gm * N + gn] = f2bf(r > 0.f ? r : 0.f);
        } else {
          size_t idx = (size_t)gm * N + gn;
          outf[idx] = val + bias[gn] + resid[idx];
        }
      }
    }
  }
}

__global__ __launch_bounds__(512, 1)
void gemm_qkv(const unsigned short* __restrict__ A, const unsigned short* __restrict__ Bt,
              int M, int N, int K, int ntx, const float* __restrict__ bias,
              const float* __restrict__ resid, float* __restrict__ outf,
              unsigned short* __restrict__ outb) {
  gemm_core<0, 256, 256, 2, 4>(A, Bt, M, N, K, ntx, bias, resid, outf, outb);
}
__global__ __launch_bounds__(512, 1)
void gemm_proj(const unsigned short* __restrict__ A, const unsigned short* __restrict__ Bt,
               int M, int N, int K, int ntx, const float* __restrict__ bias,
               const float* __restrict__ resid, float* __restrict__ outf,
               unsigned short* __restrict__ outb) {
  gemm_core<1, 256, 128, 4, 2>(A, Bt, M, N, K, ntx, bias, resid, outf, outb);
}
__global__ __launch_bounds__(512, 1)
void gemm_mlp1(const unsigned short* __restrict__ A, const unsigned short* __restrict__ Bt,
               int M, int N, int K, int ntx, const float* __restrict__ bias,
               const float* __restrict__ resid, float* __restrict__ outf,
               unsigned short* __restrict__ outb) {
  gemm_core<2, 256, 256, 2, 4>(A, Bt, M, N, K, ntx, bias, resid, outf, outb);
}
__global__ __launch_bounds__(512, 1)
void gemm_mlp2(const unsigned short* __restrict__ A, const unsigned short* __restrict__ Bt,
               int M, int N, int K, int ntx, const float* __restrict__ bias,
               const float* __restrict__ resid, float* __restrict__ outf,
               unsigned short* __restrict__ outb) {
  gemm_core<3, 256, 128, 4, 2>(A, Bt, M, N, K, ntx, bias, resid, outf, outb);
}

// ---------------- attention: one block per (b,h), 4 waves x 64 Q-rows ----------------
// Reads q/k/v from natural [NTOK][1280] layout; V transposed into swizzled LDS once.
__global__ __launch_bounds__(256)
void attn_kernel(const unsigned short* __restrict__ qkvn, unsigned short* __restrict__ o) {
  __shared__ unsigned short Vt[64 * 256];   // V^T [e][s], 16B-slot XOR swizzled
  __shared__ unsigned short Pw[4][64 * 32];
  const int bh = blockIdx.x;
  const int b = bh / 6, h = bh - b * 6;
  const unsigned short* base = qkvn + (size_t)(b * 256) * QSTR;
  const unsigned short* qb = base + h * 64;
  const unsigned short* kbp = base + 384 + h * 64;
  const unsigned short* vbp = base + 768 + h * 64;
  const int wave = threadIdx.x >> 6, lane = threadIdx.x & 63;
  const int fr = lane & 15, fg = lane >> 4;
  const int fk = fg << 3;
  const int qrow0 = wave << 6;
  const float scale = 0.051031036307982884f;  // 1/sqrt(384)
  const f32x4 z = {0.f, 0.f, 0.f, 0.f};

  // stage V^T: thread s reads V row s (64 feats), writes swizzled column
  {
    const int s = threadIdx.x;
    u16x8 v8[8];
#pragma unroll
    for (int j = 0; j < 8; ++j)
      v8[j] = *(const u16x8*)(vbp + (size_t)s * QSTR + j * 8);
#pragma unroll
    for (int e = 0; e < 64; ++e)
      Vt[(e << 8) + (s ^ ((e & 7) << 3))] = v8[e >> 3][e & 7];
  }
  __syncthreads();

  bf16x8 qf[4][2];
#pragma unroll
  for (int rb = 0; rb < 4; ++rb)
#pragma unroll
    for (int ks = 0; ks < 2; ++ks)
      qf[rb][ks] = *(const bf16x8*)(qb + (size_t)(qrow0 + rb * 16 + fr) * QSTR + ks * 32 + fk);

  float pm[4][4];
#pragma unroll
  for (int rb = 0; rb < 4; ++rb)
#pragma unroll
    for (int i = 0; i < 4; ++i) pm[rb][i] = -1e30f;

  for (int cb = 0; cb < 16; ++cb) {
    bf16x8 kf0 = *(const bf16x8*)(kbp + (size_t)(cb * 16 + fr) * QSTR + fk);
    bf16x8 kf1 = *(const bf16x8*)(kbp + (size_t)(cb * 16 + fr) * QSTR + 32 + fk);
#pragma unroll
    for (int rb = 0; rb < 4; ++rb) {
      f32x4 s = __builtin_amdgcn_mfma_f32_16x16x32_bf16(qf[rb][0], kf0, z, 0, 0, 0);
      s = __builtin_amdgcn_mfma_f32_16x16x32_bf16(qf[rb][1], kf1, s, 0, 0, 0);
#pragma unroll
      for (int i = 0; i < 4; ++i) pm[rb][i] = fmaxf(pm[rb][i], s[i]);
    }
  }
#pragma unroll
  for (int rb = 0; rb < 4; ++rb)
#pragma unroll
    for (int i = 0; i < 4; ++i) {
      float v = pm[rb][i];
      v = fmaxf(v, __shfl_xor(v, 1));
      v = fmaxf(v, __shfl_xor(v, 2));
      v = fmaxf(v, __shfl_xor(v, 4));
      v = fmaxf(v, __shfl_xor(v, 8));
      pm[rb][i] = v;
    }

  f32x4 oacc[4][4];
  float psum[4][4];
#pragma unroll
  for (int rb = 0; rb < 4; ++rb)
#pragma unroll
    for (int nb = 0; nb < 4; ++nb) oacc[rb][nb] = z;
#pragma unroll
  for (int rb = 0; rb < 4; ++rb)
#pragma unroll
    for (int i = 0; i < 4; ++i) psum[rb][i] = 0.f;

  for (int kb2 = 0; kb2 < 8; ++kb2) {
#pragma unroll
    for (int c2 = 0; c2 < 2; ++c2) {
      int cb = kb2 * 2 + c2;
      bf16x8 kf0 = *(const bf16x8*)(kbp + (size_t)(cb * 16 + fr) * QSTR + fk);
      bf16x8 kf1 = *(const bf16x8*)(kbp + (size_t)(cb * 16 + fr) * QSTR + 32 + fk);
#pragma unroll
      for (int rb = 0; rb < 4; ++rb) {
        f32x4 s = __builtin_amdgcn_mfma_f32_16x16x32_bf16(qf[rb][0], kf0, z, 0, 0, 0);
        s = __builtin_amdgcn_mfma_f32_16x16x32_bf16(qf[rb][1], kf1, s, 0, 0, 0);
#pragma unroll
        for (int i = 0; i < 4; ++i) {
          float p = __expf(scale * (s[i] - pm[rb][i]));
          psum[rb][i] += p;
          Pw[wave][(rb * 16 + (fg << 2) + i) * 32 + c2 * 16 + fr] = f2bf(p);
        }
      }
    }
    bf16x8 pa[4], vf[4];
#pragma unroll
    for (int rb = 0; rb < 4; ++rb) pa[rb] = *(const bf16x8*)(&Pw[wave][(rb * 16 + fr) * 32 + fk]);
#pragma unroll
    for (int nb = 0; nb < 4; ++nb) {
      int e = nb * 16 + fr;
      vf[nb] = *(const bf16x8*)(&Vt[(e << 8) + ((kb2 * 32 + fk) ^ ((e & 7) << 3))]);
    }
#pragma unroll
    for (int rb = 0; rb < 4; ++rb)
#pragma unroll
      for (int nb = 0; nb < 4; ++nb)
        oacc[rb][nb] = __builtin_amdgcn_mfma_f32_16x16x32_bf16(pa[rb], vf[nb], oacc[rb][nb], 0, 0, 0);
  }

  float rs[4][4];
#pragma unroll
  for (int rb = 0; rb < 4; ++rb)
#pragma unroll
    for (int i = 0; i < 4; ++i) {
      float v = psum[rb][i];
      v += __shfl_xor(v, 1);
      v += __shfl_xor(v, 2);
      v += __shfl_xor(v, 4);
      v += __shfl_xor(v, 8);
      rs[rb][i] = 1.0f / v;
    }

#pragma unroll
  for (int rb = 0; rb < 4; ++rb)
#pragma unroll
    for (int nb = 0; nb < 4; ++nb)
#pragma unroll
      for (int i = 0; i < 4; ++i) {
        int token = b * 256 + qrow0 + rb * 16 + (fg << 2) + i;
        int gcol = h * 64 + nb * 16 + fr;
        o[(size_t)token * DE + gcol] = f2bf(oacc[rb][nb][i] * rs[rb][i]);
      }
}

// ---------------- launch ----------------
extern "C" void kernel_launch(void* const* d_in, const int* in_sizes, int n_in,
                              void* d_out, int out_size, void* d_ws, size_t ws_size,
                              hipStream_t stream) {
  const float* x     = (const float*)d_in[0];
  const float* wq    = (const float*)d_in[1];
  const float* wk    = (const float*)d_in[2];
  const float* wv    = (const float*)d_in[3];
  const float* wproj = (const float*)d_in[4];
  const float* bproj = (const float*)d_in[5];
  const float* w1    = (const float*)d_in[6];
  const float* b1    = (const float*)d_in[7];
  const float* w2    = (const float*)d_in[8];
  const float* b2    = (const float*)d_in[9];
  const float* g1    = (const float*)d_in[10];
  const float* be1   = (const float*)d_in[11];
  const float* g2    = (const float*)d_in[12];
  const float* be2   = (const float*)d_in[13];

  char* ws = (char*)d_ws;
  unsigned short* xln   = (unsigned short*)(ws + 0);
  float*          x1    = (float*)(ws + 0);
  unsigned short* qkvn  = (unsigned short*)(ws + 50331648);
  unsigned short* hbuf  = (unsigned short*)(ws + 100663296);
  unsigned short* act   = (unsigned short*)(ws + 150994944);
  unsigned short* attno = (unsigned short*)(ws + 218103808);
  unsigned short* wqkvt = (unsigned short*)(ws + 352321536);
  unsigned short* wprjt = (unsigned short*)(ws + 352321536 + 983040);
  unsigned short* w1t   = (unsigned short*)(ws + 352321536 + 983040 + 294912);
  unsigned short* w2t   = (unsigned short*)(ws + 352321536 + 983040 + 294912 + 1179648);

  qkv_pack<<<(QSTR * 384 + 255) / 256, 256, 0, stream>>>(wq, wk, wv, wqkvt);
  pack_t<<<(147456 + 255) / 256, 256, 0, stream>>>(wprjt, wproj, 384, 384);
  pack_t<<<(589824 + 255) / 256, 256, 0, stream>>>(w1t, w1, 384, 1536);
  pack_t<<<(589824 + 255) / 256, 256, 0, stream>>>(w2t, w2, 1536, 384);

  ln_kernel<<<NTOK / 4, 256, 0, stream>>>(x, g1, be1, xln);

  gemm_qkv<<<5 * 256, 512, 0, stream>>>(xln, wqkvt, NTOK, QSTR, 384, 5,
                                        nullptr, nullptr, nullptr, qkvn);

  attn_kernel<<<1536, 256, 0, stream>>>(qkvn, attno);

  gemm_proj<<<3 * 256, 512, 0, stream>>>(attno, wprjt, NTOK, 384, 384, 3,
                                         bproj, x, x1, nullptr);

  ln_kernel<<<NTOK / 4, 256, 0, stream>>>(x1, g2, be2, hbuf);

  gemm_mlp1<<<6 * 256, 512, 0, stream>>>(hbuf, w1t, NTOK, 1536, 384, 6,
                                         b1, nullptr, nullptr, act);

  gemm_mlp2<<<3 * 256, 512, 0, stream>>>(act, w2t, NTOK, 384, 1536, 3,
                                         b2, x1, (float*)d_out, nullptr);
}